// Round 18
// baseline (269.441 us; speedup 1.0000x reference)
//
#include <hip/hip_runtime.h>

// ---------------------------------------------------------------------------
// Spatial Transformer Network, full f32 pipeline (round-16 proven file).
// Round 18: conv2 ci-loop split into 2 stages of 8 ci with LDS re-staging
// between them -> LDS 31.7 KB -> 15.9 KB -> 2x resident blocks/CU, better
// barrier-gap overlap. Arithmetic order per output unchanged. All other
// kernels byte-identical to round 16 (257.9 us, passed).
// ---------------------------------------------------------------------------

typedef __attribute__((ext_vector_type(2))) float f2;

#define LOAD8(dst, ptr) { \
  const float2* _p = (const float2*)(ptr); \
  float2 _a=_p[0], _b=_p[1], _c=_p[2], _d=_p[3]; \
  dst[0]=_a.x; dst[1]=_a.y; dst[2]=_b.x; dst[3]=_b.y; \
  dst[4]=_c.x; dst[5]=_c.y; dst[6]=_d.x; dst[7]=_d.y; }

// conv1 + relu + maxpool2. 16x16 pooled outputs per block.
// Output ci-planar: p1[b][oc][oy][ox], oy,ox in [0,61).
__global__ __launch_bounds__(256) void k_conv1pool(
    const float* __restrict__ x, const float* __restrict__ w,
    const float* __restrict__ bias, float* __restrict__ p1)
{
  __shared__ float s_in[3 * 38 * 38];  // 17328 B, [ci][r][c]
  const int b = blockIdx.z;
  const int ty0 = blockIdx.y * 16, tx0 = blockIdx.x * 16;
  const int tid = threadIdx.x;

  const float* xb = x + b * (128 * 128 * 3);
  const int r0 = ty0 * 2, c0 = tx0 * 2;
  for (int i = tid; i < 4332; i += 256) {
    int ci = i / 1444;
    int rc = i - ci * 1444;
    int r = rc / 38, c = rc - r * 38;
    int gr = r0 + r, gc = c0 + c;
    float v = 0.f;
    if (gr < 128 && gc < 128) v = xb[(gr * 128 + gc) * 3 + ci];
    s_in[i] = v;
  }
  __syncthreads();

  const int lx = tid & 15, ly = tid >> 4;
  const int bc = 2 * lx, br = 2 * ly;

  f2 a00[8], a01[8], a10[8], a11[8];
#pragma unroll
  for (int j = 0; j < 8; ++j) {
    a00[j] = (f2)0.f; a01[j] = (f2)0.f; a10[j] = (f2)0.f; a11[j] = (f2)0.f;
  }

#pragma unroll 1
  for (int ci = 0; ci < 3; ++ci) {
    const float* base = s_in + ci * 1444 + br * 38 + bc;
    float rA[8], rB[8];
    LOAD8(rA, base);
#pragma unroll 1
    for (int ky = 0; ky < 7; ++ky) {
      LOAD8(rB, base + (ky + 1) * 38);
#pragma unroll
      for (int kx = 0; kx < 7; ++kx) {
        const f2* w2p = (const f2*)(w + ((ky * 7 + kx) * 3 + ci) * 16);
        f2 i00 = (f2)(rA[kx]), i01 = (f2)(rA[kx + 1]);
        f2 i10 = (f2)(rB[kx]), i11 = (f2)(rB[kx + 1]);
#pragma unroll
        for (int j = 0; j < 8; ++j) {
          f2 wv = w2p[j];
          a00[j] = __builtin_elementwise_fma(i00, wv, a00[j]);
          a01[j] = __builtin_elementwise_fma(i01, wv, a01[j]);
          a10[j] = __builtin_elementwise_fma(i10, wv, a10[j]);
          a11[j] = __builtin_elementwise_fma(i11, wv, a11[j]);
        }
      }
#pragma unroll
      for (int t = 0; t < 8; ++t) rA[t] = rB[t];
    }
  }

  const int oy = ty0 + ly, ox = tx0 + lx;
  if (oy < 61 && ox < 61) {
    float* ob = p1 + (b * 16) * 3721 + oy * 61 + ox;
#pragma unroll
    for (int j = 0; j < 16; ++j) {
      float m = fmaxf(fmaxf(a00[j >> 1][j & 1], a01[j >> 1][j & 1]),
                      fmaxf(a10[j >> 1][j & 1], a11[j >> 1][j & 1]));
      ob[j * 3721] = fmaxf(m + bias[j], 0.f);
    }
  }
}

// conv2 + relu + maxpool2. Block = 2 pooled rows x 28 cols x all 32 oc.
// ci split into 2 stages of 8 (LDS 15.9 KB -> 2x occupancy); accumulators
// persist in registers across the split. Output p2 NHWC-flat.
__global__ __launch_bounds__(256) void k_conv2pool(
    const float* __restrict__ p1, const float* __restrict__ w,
    const float* __restrict__ bias, float* __restrict__ p2)
{
  __shared__ float s_in[8 * 8 * 62];  // 15872 B, [ci][r][c62]
  const int rt = blockIdx.x, b = blockIdx.y;
  const int tid = threadIdx.x;

  const float* pb = p1 + b * 59536 + (rt * 4) * 61;  // input rows 4rt..4rt+7 (<=59)

  const int lane = tid & 63;
  const int oc0 = __builtin_amdgcn_readfirstlane((tid >> 6) * 8);
  const bool act = lane < 56;
  const int p = act ? lane : 55;
  const int pr = p / 28, cx = p - pr * 28;

  f2 a00[4], a01[4], a10[4], a11[4];
#pragma unroll
  for (int q = 0; q < 4; ++q) {
    a00[q] = (f2)0.f; a01[q] = (f2)0.f; a10[q] = (f2)0.f; a11[q] = (f2)0.f;
  }

#pragma unroll 1
  for (int half = 0; half < 2; ++half) {
    if (half) __syncthreads();          // all reads of previous half done
    for (int i = tid; i < 3904; i += 256) {  // 8*8*61
      int ci = i / 488;
      int rem = i - ci * 488;
      int r = rem / 61, c = rem - r * 61;
      s_in[ci * 496 + r * 62 + c] = pb[(half * 8 + ci) * 3721 + r * 61 + c];
    }
    __syncthreads();

#pragma unroll 2
    for (int ci = 0; ci < 8; ++ci) {
      const float* base = s_in + ci * 496 + (2 * pr) * 62 + 2 * cx;
      float r[6][6];
#pragma unroll
      for (int rr = 0; rr < 6; ++rr) {
        const float2* q2 = (const float2*)(base + rr * 62);
        float2 va = q2[0], vb = q2[1], vc = q2[2];
        r[rr][0] = va.x; r[rr][1] = va.y; r[rr][2] = vb.x;
        r[rr][3] = vb.y; r[rr][4] = vc.x; r[rr][5] = vc.y;
      }
#pragma unroll
      for (int ky = 0; ky < 5; ++ky) {
#pragma unroll
        for (int kx = 0; kx < 5; ++kx) {
          const f2* w2p = (const f2*)(w + ((ky * 5 + kx) * 16 + half * 8 + ci) * 32 + oc0);
          f2 i00 = (f2)(r[ky][kx]),     i01 = (f2)(r[ky][kx + 1]);
          f2 i10 = (f2)(r[ky + 1][kx]), i11 = (f2)(r[ky + 1][kx + 1]);
#pragma unroll
          for (int q = 0; q < 4; ++q) {
            f2 wv = w2p[q];
            a00[q] = __builtin_elementwise_fma(i00, wv, a00[q]);
            a01[q] = __builtin_elementwise_fma(i01, wv, a01[q]);
            a10[q] = __builtin_elementwise_fma(i10, wv, a10[q]);
            a11[q] = __builtin_elementwise_fma(i11, wv, a11[q]);
          }
        }
      }
    }
  }

  if (act) {
    const int opy = rt * 2 + pr;
    float* ob = p2 + b * 25088 + (opy * 28 + cx) * 32 + oc0;
#pragma unroll
    for (int q = 0; q < 8; ++q) {
      float m = fmaxf(fmaxf(a00[q >> 1][q & 1], a01[q >> 1][q & 1]),
                      fmaxf(a10[q >> 1][q & 1], a11[q >> 1][q & 1]));
      ob[q] = fmaxf(m + bias[oc0 + q], 0.f);
    }
  }
}

// fc1 partial sums (proven structure; unroll 8).
__global__ __launch_bounds__(256) void k_fc1(
    const float* __restrict__ h, const float* __restrict__ w,
    float* __restrict__ partial)
{
  const int kc = blockIdx.x, bg = blockIdx.y;
  const int b0 = bg * 8, k0 = kc * 1568;
  const int wv = threadIdx.x >> 6, lane = threadIdx.x & 63;
  const int n = lane;
  const bool act = n < 50;
  const int ne = act ? n : 0;

  float acc[8];
#pragma unroll
  for (int j = 0; j < 8; ++j) acc[j] = 0.f;

  const float* hb = h + b0 * 25088;
#pragma unroll 8
  for (int i = 0; i < 392; ++i) {
    int k = k0 + wv + 4 * i;
    int ks = __builtin_amdgcn_readfirstlane(k);
    float wval = w[k * 50 + ne];
#pragma unroll
    for (int j = 0; j < 8; ++j)
      acc[j] = fmaf(hb[j * 25088 + ks], wval, acc[j]);
  }

  __shared__ float red[4 * 8 * 50];
  if (act) {
#pragma unroll
    for (int j = 0; j < 8; ++j) red[(wv * 8 + j) * 50 + n] = acc[j];
  }
  __syncthreads();
  for (int t = threadIdx.x; t < 400; t += 256) {
    int j = t / 50, n2 = t - j * 50;
    float s = red[j * 50 + n2] + red[(8 + j) * 50 + n2] +
              red[(16 + j) * 50 + n2] + red[(24 + j) * 50 + n2];
    partial[(kc * 128 + b0 + j) * 50 + n2] = s;
  }
}

// fc2: reduce 16 k-chunk partials + bias + relu, then 50x6 matmul -> theta.
__global__ __launch_bounds__(64) void k_fc2(
    const float* __restrict__ partial, const float* __restrict__ b1,
    const float* __restrict__ w2, const float* __restrict__ b2,
    float* __restrict__ theta)
{
  const int b = blockIdx.x;
  const int lane = threadIdx.x;
  __shared__ float hh[50];
  if (lane < 50) {
    float s = b1[lane];
    for (int kc = 0; kc < 16; ++kc) s += partial[(kc * 128 + b) * 50 + lane];
    hh[lane] = fmaxf(s, 0.f);
  }
  __syncthreads();
  if (lane < 6) {
    float s = b2[lane];
    for (int k = 0; k < 50; ++k) s = fmaf(hh[k], w2[k * 6 + lane], s);
    theta[b * 6 + lane] = s;
  }
}

// Affine grid + bilinear sample. One thread per output pixel (3 channels).
__global__ __launch_bounds__(256) void k_sample(
    const float* __restrict__ x, const float* __restrict__ theta,
    float* __restrict__ out)
{
  const int b = blockIdx.y;
  const int p = blockIdx.x * 256 + threadIdx.x;  // 0..16383
  const int oy = p >> 7, ox = p & 127;
  const float* th = theta + b * 6;
  const float t0 = th[0], t1 = th[1], t2 = th[2];
  const float t3 = th[3], t4 = th[4], t5 = th[5];

  const float gx = -1.f + (float)ox * (2.f / 127.f);
  const float gy = -1.f + (float)oy * (2.f / 127.f);
  const float xs = t0 * gx + t1 * gy + t2;
  const float ys = t3 * gx + t4 * gy + t5;
  const float xp = (xs + 1.f) * 63.5f;
  const float yp = (ys + 1.f) * 63.5f;
  const float x0f = floorf(xp), y0f = floorf(yp);
  const float wx = xp - x0f, wy = yp - y0f;
  int x0i = (int)x0f; x0i = x0i < 0 ? 0 : (x0i > 127 ? 127 : x0i);
  int y0i = (int)y0f; y0i = y0i < 0 ? 0 : (y0i > 127 ? 127 : y0i);
  const int x1i = x0i + 1 > 127 ? 127 : x0i + 1;
  const int y1i = y0i + 1 > 127 ? 127 : y0i + 1;

  const float wa = (1.f - wx) * (1.f - wy);
  const float wb = (1.f - wx) * wy;
  const float wc = wx * (1.f - wy);
  const float wd = wx * wy;

  const float* img = x + b * (128 * 128 * 3);
  const float* pa = img + (y0i * 128 + x0i) * 3;
  const float* pb = img + (y1i * 128 + x0i) * 3;
  const float* pc = img + (y0i * 128 + x1i) * 3;
  const float* pd = img + (y1i * 128 + x1i) * 3;

  float* o = out + (b * 16384 + p) * 3;
#pragma unroll
  for (int ch = 0; ch < 3; ++ch)
    o[ch] = pa[ch] * wa + pb[ch] * wb + pc[ch] * wc + pd[ch] * wd;
}

extern "C" void kernel_launch(void* const* d_in, const int* in_sizes, int n_in,
                              void* d_out, int out_size, void* d_ws, size_t ws_size,
                              hipStream_t stream) {
  const float* x   = (const float*)d_in[0];
  const float* w1  = (const float*)d_in[1];
  const float* b1  = (const float*)d_in[2];
  const float* w2  = (const float*)d_in[3];
  const float* b2  = (const float*)d_in[4];
  const float* wf1 = (const float*)d_in[5];
  const float* bf1 = (const float*)d_in[6];
  const float* wf2 = (const float*)d_in[7];
  const float* bf2 = (const float*)d_in[8];

  float* ws      = (float*)d_ws;
  float* p1      = ws;                   // 128*16*61*61      = 7,620,608 f
  float* p2      = p1 + 7620608;         // 128*25088         = 3,211,264 f
  float* partial = p2 + 3211264;         // 16*128*50         =   102,400 f
  float* theta   = partial + 102400;     // 128*6             =       768 f
  float* out     = (float*)d_out;

  k_conv1pool<<<dim3(4, 4, 128), 256, 0, stream>>>(x, w1, b1, p1);
  k_conv2pool<<<dim3(14, 128), 256, 0, stream>>>(p1, w2, b2, p2);
  k_fc1<<<dim3(16, 16), 256, 0, stream>>>(p2, wf1, partial);
  k_fc2<<<128, 64, 0, stream>>>(partial, bf1, wf2, bf2, theta);
  k_sample<<<dim3(64, 128), 256, 0, stream>>>(x, theta, out);
}

// Round 19
// 257.830 us; speedup vs baseline: 1.0450x; 1.0450x over previous
//
#include <hip/hip_runtime.h>

// ---------------------------------------------------------------------------
// Spatial Transformer Network, full f32 pipeline — FINAL (round-16 file).
// Best proven state: 257.9 us. conv2 @ 77% VALUBusy ~ 85% of the measured
// 103 TF f32-FMA ceiling. All 2x-precision paths (fdot2, f16/bf16 MFMA,
// pk_fma_f32) condemned by experiment in this harness; occupancy lever
// closed (grid = 7 blocks/CU caps residency). See session ledger r5-r18.
// ---------------------------------------------------------------------------

typedef __attribute__((ext_vector_type(2))) float f2;

#define LOAD8(dst, ptr) { \
  const float2* _p = (const float2*)(ptr); \
  float2 _a=_p[0], _b=_p[1], _c=_p[2], _d=_p[3]; \
  dst[0]=_a.x; dst[1]=_a.y; dst[2]=_b.x; dst[3]=_b.y; \
  dst[4]=_c.x; dst[5]=_c.y; dst[6]=_d.x; dst[7]=_d.y; }

// conv1 + relu + maxpool2. 16x16 pooled outputs per block.
// Output ci-planar: p1[b][oc][oy][ox], oy,ox in [0,61).
__global__ __launch_bounds__(256) void k_conv1pool(
    const float* __restrict__ x, const float* __restrict__ w,
    const float* __restrict__ bias, float* __restrict__ p1)
{
  __shared__ float s_in[3 * 38 * 38];  // 17328 B, [ci][r][c]
  const int b = blockIdx.z;
  const int ty0 = blockIdx.y * 16, tx0 = blockIdx.x * 16;
  const int tid = threadIdx.x;

  const float* xb = x + b * (128 * 128 * 3);
  const int r0 = ty0 * 2, c0 = tx0 * 2;
  for (int i = tid; i < 4332; i += 256) {
    int ci = i / 1444;
    int rc = i - ci * 1444;
    int r = rc / 38, c = rc - r * 38;
    int gr = r0 + r, gc = c0 + c;
    float v = 0.f;
    if (gr < 128 && gc < 128) v = xb[(gr * 128 + gc) * 3 + ci];
    s_in[i] = v;
  }
  __syncthreads();

  const int lx = tid & 15, ly = tid >> 4;
  const int bc = 2 * lx, br = 2 * ly;

  f2 a00[8], a01[8], a10[8], a11[8];
#pragma unroll
  for (int j = 0; j < 8; ++j) {
    a00[j] = (f2)0.f; a01[j] = (f2)0.f; a10[j] = (f2)0.f; a11[j] = (f2)0.f;
  }

#pragma unroll 1
  for (int ci = 0; ci < 3; ++ci) {
    const float* base = s_in + ci * 1444 + br * 38 + bc;
    float rA[8], rB[8];
    LOAD8(rA, base);
#pragma unroll 1
    for (int ky = 0; ky < 7; ++ky) {
      LOAD8(rB, base + (ky + 1) * 38);
#pragma unroll
      for (int kx = 0; kx < 7; ++kx) {
        const f2* w2p = (const f2*)(w + ((ky * 7 + kx) * 3 + ci) * 16);
        f2 i00 = (f2)(rA[kx]), i01 = (f2)(rA[kx + 1]);
        f2 i10 = (f2)(rB[kx]), i11 = (f2)(rB[kx + 1]);
#pragma unroll
        for (int j = 0; j < 8; ++j) {
          f2 wv = w2p[j];
          a00[j] = __builtin_elementwise_fma(i00, wv, a00[j]);
          a01[j] = __builtin_elementwise_fma(i01, wv, a01[j]);
          a10[j] = __builtin_elementwise_fma(i10, wv, a10[j]);
          a11[j] = __builtin_elementwise_fma(i11, wv, a11[j]);
        }
      }
#pragma unroll
      for (int t = 0; t < 8; ++t) rA[t] = rB[t];
    }
  }

  const int oy = ty0 + ly, ox = tx0 + lx;
  if (oy < 61 && ox < 61) {
    float* ob = p1 + (b * 16) * 3721 + oy * 61 + ox;
#pragma unroll
    for (int j = 0; j < 16; ++j) {
      float m = fmaxf(fmaxf(a00[j >> 1][j & 1], a01[j >> 1][j & 1]),
                      fmaxf(a10[j >> 1][j & 1], a11[j >> 1][j & 1]));
      ob[j * 3721] = fmaxf(m + bias[j], 0.f);
    }
  }
}

// conv2 + relu + maxpool2. Block = 2 pooled rows x 28 cols x all 32 oc.
// Output p2[b][oy][ox][oc] NHWC-flat (fc1 flatten order).
__global__ __launch_bounds__(256) void k_conv2pool(
    const float* __restrict__ p1, const float* __restrict__ w,
    const float* __restrict__ bias, float* __restrict__ p2)
{
  __shared__ float s_in[16 * 8 * 62];  // 31744 B, [ci][r][c62]
  const int rt = blockIdx.x, b = blockIdx.y;
  const int tid = threadIdx.x;

  const float* pb = p1 + b * 59536 + (rt * 4) * 61;  // input rows 4rt..4rt+7 (<=59)
  for (int i = tid; i < 7808; i += 256) {            // 16*8*61
    int ci = i / 488;
    int rem = i - ci * 488;
    int r = rem / 61, c = rem - r * 61;
    s_in[ci * 496 + r * 62 + c] = pb[ci * 3721 + r * 61 + c];
  }
  __syncthreads();

  const int lane = tid & 63;
  const int oc0 = __builtin_amdgcn_readfirstlane((tid >> 6) * 8);
  const bool act = lane < 56;
  const int p = act ? lane : 55;
  const int pr = p / 28, cx = p - pr * 28;

  f2 a00[4], a01[4], a10[4], a11[4];
#pragma unroll
  for (int q = 0; q < 4; ++q) {
    a00[q] = (f2)0.f; a01[q] = (f2)0.f; a10[q] = (f2)0.f; a11[q] = (f2)0.f;
  }

#pragma unroll 2
  for (int ci = 0; ci < 16; ++ci) {
    const float* base = s_in + ci * 496 + (2 * pr) * 62 + 2 * cx;
    float r[6][6];
#pragma unroll
    for (int rr = 0; rr < 6; ++rr) {
      const float2* q2 = (const float2*)(base + rr * 62);
      float2 va = q2[0], vb = q2[1], vc = q2[2];
      r[rr][0] = va.x; r[rr][1] = va.y; r[rr][2] = vb.x;
      r[rr][3] = vb.y; r[rr][4] = vc.x; r[rr][5] = vc.y;
    }
#pragma unroll
    for (int ky = 0; ky < 5; ++ky) {
#pragma unroll
      for (int kx = 0; kx < 5; ++kx) {
        const f2* w2p = (const f2*)(w + ((ky * 5 + kx) * 16 + ci) * 32 + oc0);
        f2 i00 = (f2)(r[ky][kx]),     i01 = (f2)(r[ky][kx + 1]);
        f2 i10 = (f2)(r[ky + 1][kx]), i11 = (f2)(r[ky + 1][kx + 1]);
#pragma unroll
        for (int q = 0; q < 4; ++q) {
          f2 wv = w2p[q];
          a00[q] = __builtin_elementwise_fma(i00, wv, a00[q]);
          a01[q] = __builtin_elementwise_fma(i01, wv, a01[q]);
          a10[q] = __builtin_elementwise_fma(i10, wv, a10[q]);
          a11[q] = __builtin_elementwise_fma(i11, wv, a11[q]);
        }
      }
    }
  }

  if (act) {
    const int opy = rt * 2 + pr;
    float* ob = p2 + b * 25088 + (opy * 28 + cx) * 32 + oc0;
#pragma unroll
    for (int q = 0; q < 8; ++q) {
      float m = fmaxf(fmaxf(a00[q >> 1][q & 1], a01[q >> 1][q & 1]),
                      fmaxf(a10[q >> 1][q & 1], a11[q >> 1][q & 1]));
      ob[q] = fmaxf(m + bias[oc0 + q], 0.f);
    }
  }
}

// fc1 partial sums (proven structure; unroll 8).
__global__ __launch_bounds__(256) void k_fc1(
    const float* __restrict__ h, const float* __restrict__ w,
    float* __restrict__ partial)
{
  const int kc = blockIdx.x, bg = blockIdx.y;
  const int b0 = bg * 8, k0 = kc * 1568;
  const int wv = threadIdx.x >> 6, lane = threadIdx.x & 63;
  const int n = lane;
  const bool act = n < 50;
  const int ne = act ? n : 0;

  float acc[8];
#pragma unroll
  for (int j = 0; j < 8; ++j) acc[j] = 0.f;

  const float* hb = h + b0 * 25088;
#pragma unroll 8
  for (int i = 0; i < 392; ++i) {
    int k = k0 + wv + 4 * i;
    int ks = __builtin_amdgcn_readfirstlane(k);
    float wval = w[k * 50 + ne];
#pragma unroll
    for (int j = 0; j < 8; ++j)
      acc[j] = fmaf(hb[j * 25088 + ks], wval, acc[j]);
  }

  __shared__ float red[4 * 8 * 50];
  if (act) {
#pragma unroll
    for (int j = 0; j < 8; ++j) red[(wv * 8 + j) * 50 + n] = acc[j];
  }
  __syncthreads();
  for (int t = threadIdx.x; t < 400; t += 256) {
    int j = t / 50, n2 = t - j * 50;
    float s = red[j * 50 + n2] + red[(8 + j) * 50 + n2] +
              red[(16 + j) * 50 + n2] + red[(24 + j) * 50 + n2];
    partial[(kc * 128 + b0 + j) * 50 + n2] = s;
  }
}

// fc2: reduce 16 k-chunk partials + bias + relu, then 50x6 matmul -> theta.
__global__ __launch_bounds__(64) void k_fc2(
    const float* __restrict__ partial, const float* __restrict__ b1,
    const float* __restrict__ w2, const float* __restrict__ b2,
    float* __restrict__ theta)
{
  const int b = blockIdx.x;
  const int lane = threadIdx.x;
  __shared__ float hh[50];
  if (lane < 50) {
    float s = b1[lane];
    for (int kc = 0; kc < 16; ++kc) s += partial[(kc * 128 + b) * 50 + lane];
    hh[lane] = fmaxf(s, 0.f);
  }
  __syncthreads();
  if (lane < 6) {
    float s = b2[lane];
    for (int k = 0; k < 50; ++k) s = fmaf(hh[k], w2[k * 6 + lane], s);
    theta[b * 6 + lane] = s;
  }
}

// Affine grid + bilinear sample. One thread per output pixel (3 channels).
__global__ __launch_bounds__(256) void k_sample(
    const float* __restrict__ x, const float* __restrict__ theta,
    float* __restrict__ out)
{
  const int b = blockIdx.y;
  const int p = blockIdx.x * 256 + threadIdx.x;  // 0..16383
  const int oy = p >> 7, ox = p & 127;
  const float* th = theta + b * 6;
  const float t0 = th[0], t1 = th[1], t2 = th[2];
  const float t3 = th[3], t4 = th[4], t5 = th[5];

  const float gx = -1.f + (float)ox * (2.f / 127.f);
  const float gy = -1.f + (float)oy * (2.f / 127.f);
  const float xs = t0 * gx + t1 * gy + t2;
  const float ys = t3 * gx + t4 * gy + t5;
  const float xp = (xs + 1.f) * 63.5f;
  const float yp = (ys + 1.f) * 63.5f;
  const float x0f = floorf(xp), y0f = floorf(yp);
  const float wx = xp - x0f, wy = yp - y0f;
  int x0i = (int)x0f; x0i = x0i < 0 ? 0 : (x0i > 127 ? 127 : x0i);
  int y0i = (int)y0f; y0i = y0i < 0 ? 0 : (y0i > 127 ? 127 : y0i);
  const int x1i = x0i + 1 > 127 ? 127 : x0i + 1;
  const int y1i = y0i + 1 > 127 ? 127 : y0i + 1;

  const float wa = (1.f - wx) * (1.f - wy);
  const float wb = (1.f - wx) * wy;
  const float wc = wx * (1.f - wy);
  const float wd = wx * wy;

  const float* img = x + b * (128 * 128 * 3);
  const float* pa = img + (y0i * 128 + x0i) * 3;
  const float* pb = img + (y1i * 128 + x0i) * 3;
  const float* pc = img + (y0i * 128 + x1i) * 3;
  const float* pd = img + (y1i * 128 + x1i) * 3;

  float* o = out + (b * 16384 + p) * 3;
#pragma unroll
  for (int ch = 0; ch < 3; ++ch)
    o[ch] = pa[ch] * wa + pb[ch] * wb + pc[ch] * wc + pd[ch] * wd;
}

extern "C" void kernel_launch(void* const* d_in, const int* in_sizes, int n_in,
                              void* d_out, int out_size, void* d_ws, size_t ws_size,
                              hipStream_t stream) {
  const float* x   = (const float*)d_in[0];
  const float* w1  = (const float*)d_in[1];
  const float* b1  = (const float*)d_in[2];
  const float* w2  = (const float*)d_in[3];
  const float* b2  = (const float*)d_in[4];
  const float* wf1 = (const float*)d_in[5];
  const float* bf1 = (const float*)d_in[6];
  const float* wf2 = (const float*)d_in[7];
  const float* bf2 = (const float*)d_in[8];

  float* ws      = (float*)d_ws;
  float* p1      = ws;                   // 128*16*61*61      = 7,620,608 f
  float* p2      = p1 + 7620608;         // 128*25088         = 3,211,264 f
  float* partial = p2 + 3211264;         // 16*128*50         =   102,400 f
  float* theta   = partial + 102400;     // 128*6             =       768 f
  float* out     = (float*)d_out;

  k_conv1pool<<<dim3(4, 4, 128), 256, 0, stream>>>(x, w1, b1, p1);
  k_conv2pool<<<dim3(14, 128), 256, 0, stream>>>(p1, w2, b2, p2);
  k_fc1<<<dim3(16, 16), 256, 0, stream>>>(p2, wf1, partial);
  k_fc2<<<128, 64, 0, stream>>>(partial, bf1, wf2, bf2, theta);
  k_sample<<<dim3(64, 128), 256, 0, stream>>>(x, theta, out);
}